// Round 21
// baseline (109.633 us; speedup 1.0000x reference)
//
#include <hip/hip_runtime.h>
#include <hip/hip_bf16.h>
#include <math.h>

#define D_MODEL 1024
#define C_DIM   128
#define BATCH   4
#define SEQ     2048
#define BS_ROWS (BATCH*SEQ)

typedef float  f32x4 __attribute__((ext_vector_type(4)));
typedef short  s16x8 __attribute__((ext_vector_type(8)));
typedef unsigned short u16;
typedef unsigned short u16x4 __attribute__((ext_vector_type(4)));

__device__ inline u16 f2bf(float f){
    unsigned u = __builtin_bit_cast(unsigned, f);
    u += 0x7FFF + ((u >> 16) & 1);          // round-to-nearest-even
    return (u16)(u >> 16);
}

// async global->LDS, 16B per lane; LDS dest = wave-uniform base + lane*16
__device__ inline void gl_lds16(const u16* g, u16* l){
    __builtin_amdgcn_global_load_lds(
        (const __attribute__((address_space(1))) void*)g,
        (__attribute__((address_space(3))) void*)l,
        16, 0, 0);
}

// counted vmem wait: wait until <= N vmem instrs outstanding (this wave)
template<int N> __device__ inline void wait_vm(){
    if constexpr (N <= 0)      asm volatile("s_waitcnt vmcnt(0)" ::: "memory");
    else if constexpr (N == 4) asm volatile("s_waitcnt vmcnt(4)" ::: "memory");
    else if constexpr (N == 8) asm volatile("s_waitcnt vmcnt(8)" ::: "memory");
    else                       asm volatile("s_waitcnt vmcnt(0)" ::: "memory");
}

// ---------------------------------------------------------------------------
// gemm_core: verified round-12/15 body (static disjoint double buffers,
// 2x-unrolled K-loop, counted vmcnt(NL), raw barriers, hoisted pointers).
// kt0/nktIn: LOCAL K-chunk start tile and length (both applied uniformly to
// A and B staging; any batch base offsets must be pre-applied to Aa/Bb).
// ATOMIC: fp32 atomicAdd epilogue (split-K partials into zeroed C).
// ---------------------------------------------------------------------------
template<int BM, int BN, int WM, int WN, int OUT_BF16, int MASK, int CK,
         int EXPSUM, int RSCALE, int ATOMIC>
__device__ __forceinline__ void gemm_core(
    u16 (&As0)[BM*64], u16 (&As1)[BM*64],
    u16 (&Bs0)[BN*64], u16 (&Bs1)[BN*64],
    const u16* __restrict__ Aa, const u16* __restrict__ Bb,
    void* __restrict__ Cout, const float* __restrict__ mp,
    float* __restrict__ rowsum,
    int mt, int nt, int K, int lda, int ldb, int ldc, float scale,
    int kt0, int nktIn)
{
    constexpr int W  = WM * WN;
    constexpr int PM = BM / WM, PN = BN / WN;
    constexpr int FM = PM / 16, FN = PN / 16;
    constexpr int CA = BM / 8 / W;          // A chunks (1KB) per wave per stage
    constexpr int CB = BN / 8 / W;
    constexpr int NL = CA + CB;             // gl_lds instrs per wave per stage
    constexpr int ASZ = BM * 64, BSZ = BN * 64;

    const int tid = threadIdx.x, lane = tid & 63, wave = tid >> 6;
    const int wr = wave / WN, wc = wave % WN;
    const int mbase = mt * BM, nbase = nt * BN;
    int nkt;
    if (nktIn > 0) nkt = nktIn;
    else {
        int Keff = K;
        if (CK) { int ke = (mt + 1) * BM; Keff = ke < K ? ke : K; }
        nkt = Keff >> 6;                    // even by construction
    }

    f32x4 acc[FM][FN];
    #pragma unroll
    for (int m = 0; m < FM; ++m)
        #pragma unroll
        for (int n = 0; n < FN; ++n) acc[m][n] = (f32x4){0.f,0.f,0.f,0.f};

    const int sr  = lane >> 3;                 // row within 8-row chunk
    const int sc8 = (lane & 7) ^ sr;           // XOR-swizzled 16B col slot

    // hoisted staging pointers: one per chunk, advanced 64 elts per STAGE
    const u16* aptr[CA];
    const u16* bptr[CB];
    #pragma unroll
    for (int s = 0; s < CA; ++s)
        aptr[s] = Aa + (size_t)(mbase + (wave * CA + s) * 8 + sr) * lda + kt0 * 64 + sc8 * 8;
    #pragma unroll
    for (int s = 0; s < CB; ++s)
        bptr[s] = Bb + (size_t)(nbase + (wave * CB + s) * 8 + sr) * ldb + kt0 * 64 + sc8 * 8;

    auto STAGE = [&](u16 (&Ad)[ASZ], u16 (&Bd)[BSZ]) {
        #pragma unroll
        for (int s = 0; s < CA; ++s) { gl_lds16(aptr[s], &Ad[(wave * CA + s) * 512]); aptr[s] += 64; }
        #pragma unroll
        for (int s = 0; s < CB; ++s) { gl_lds16(bptr[s], &Bd[(wave * CB + s) * 512]); bptr[s] += 64; }
    };

    auto COMPUTE = [&](const u16 (&Ap)[ASZ], const u16 (&Bp)[BSZ]) {
        #pragma unroll
        for (int ks = 0; ks < 2; ++ks) {
            s16x8 af[FM], bfr[FN];
            const int k8 = ks * 4 + (lane >> 4);
            #pragma unroll
            for (int m = 0; m < FM; ++m) {
                const int row = wr * PM + m * 16 + (lane & 15);
                af[m] = *(const s16x8*)&Ap[row * 64 + ((k8 ^ (row & 7)) << 3)];
            }
            #pragma unroll
            for (int n = 0; n < FN; ++n) {
                const int row = wc * PN + n * 16 + (lane & 15);
                bfr[n] = *(const s16x8*)&Bp[row * 64 + ((k8 ^ (row & 7)) << 3)];
            }
            #pragma unroll
            for (int m = 0; m < FM; ++m)
                #pragma unroll
                for (int n = 0; n < FN; ++n)
                    acc[m][n] = __builtin_amdgcn_mfma_f32_16x16x32_bf16(af[m], bfr[n], acc[m][n], 0, 0, 0);
        }
    };

    // prologue: tile 0 into buf0
    STAGE(As0, Bs0);
    for (int t = 0; t < nkt; t += 2) {
        STAGE(As1, Bs1);                 // t+1 < nkt always (nkt even)
        wait_vm<NL>();                   // retire tile t's loads only
        __builtin_amdgcn_s_barrier();    // buf0 complete for all waves
        COMPUTE(As0, Bs0);
        __builtin_amdgcn_s_barrier();    // all waves done reading buf0
        if (t + 2 < nkt) { STAGE(As0, Bs0); wait_vm<NL>(); }
        else             { wait_vm<0>(); }
        __builtin_amdgcn_s_barrier();    // buf1 complete
        COMPUTE(As1, Bs1);
        __builtin_amdgcn_s_barrier();    // all waves done reading buf1
    }

    // epilogue: C/D layout col=lane&15, row=(lane>>4)*4+r (m89-verified)
    const int lr = (lane >> 4) * 4, lc = lane & 15;
    float rs[FM][4];
    if (EXPSUM) {
        #pragma unroll
        for (int m = 0; m < FM; ++m)
            #pragma unroll
            for (int r = 0; r < 4; ++r) rs[m][r] = 0.f;
    }
    #pragma unroll
    for (int m = 0; m < FM; ++m) {
        #pragma unroll
        for (int n = 0; n < FN; ++n) {
            const int gr = mbase + wr * PM + m * 16 + lr;
            const int gc = nbase + wc * PN + n * 16 + lc;
            #pragma unroll
            for (int r = 0; r < 4; ++r) {
                float f = acc[m][n][r] * scale;
                if (EXPSUM) {
                    f = (gc <= gr + r) ? __expf(f) : 0.f;   // causal + exp
                    rs[m][r] += f;
                }
                if (RSCALE) f /= rowsum[gr + r];
                const size_t off = (size_t)(gr + r) * ldc + gc;
                if (MASK) { if (mp) f *= mp[off]; }
                if (ATOMIC)        atomicAdd(&((float*)Cout)[off], f);
                else if (OUT_BF16) ((u16*)Cout)[off] = f2bf(f);
                else               ((float*)Cout)[off] = f;
            }
        }
    }
    if (EXPSUM) {
        #pragma unroll
        for (int m = 0; m < FM; ++m) {
            #pragma unroll
            for (int r = 0; r < 4; ++r) {
                float v = rs[m][r];
                v += __shfl_xor(v, 1); v += __shfl_xor(v, 2);
                v += __shfl_xor(v, 4); v += __shfl_xor(v, 8);
                if ((lane & 15) == 0) {
                    const int gr = mbase + wr * PM + m * 16 + lr + r;
                    atomicAdd(rowsum + gr, v);
                }
            }
        }
    }
}

// ---------------------------------------------------------------------------
// qk projection wrapper (round-12 verified decode, ORD=1)
// ---------------------------------------------------------------------------
__launch_bounds__(256)
__global__ void qk_proj(const u16* __restrict__ xb, const u16* __restrict__ AbT,
                        const u16* __restrict__ Bmb,
                        u16* __restrict__ qm, u16* __restrict__ kk,
                        const float* __restrict__ maskp)
{
    __shared__ u16 As0[64*64];
    __shared__ u16 As1[64*64];
    __shared__ u16 Bs0[64*64];
    __shared__ u16 Bs1[64*64];

    const int nwg = gridDim.x;
    const int l   = (blockIdx.x & 7) * (nwg >> 3) + (blockIdx.x >> 3);
    const int nty = l % 4;                   // path*2 + nt
    const int mt  = l / 4;
    const int path = nty >> 1, nt = nty & 1;

    const u16* Bb = path ? Bmb : AbT;
    void* Cout = path ? (void*)kk : (void*)qm;
    const float* mp = path ? nullptr : maskp;

    gemm_core<64,64,2,2, 1,1,0,0,0,0>(
        As0, As1, Bs0, Bs1, xb, Bb, Cout, mp, nullptr,
        mt, nt, D_MODEL, D_MODEL, D_MODEL, C_DIM, 1.0f, 0, 0);
}

// ---------------------------------------------------------------------------
// Fused scores + xovT dispatch, LPT-ordered (round-18 verified).
// ---------------------------------------------------------------------------
__launch_bounds__(256)
__global__ void scores_xov_fused(const u16* __restrict__ qm,
                                 const u16* __restrict__ kk,
                                 u16* __restrict__ sc,
                                 float* __restrict__ rowsum,
                                 const u16* __restrict__ ovT,
                                 const u16* __restrict__ xb,
                                 u16* __restrict__ xovT)
{
    __shared__ u16 As0[128*64];
    __shared__ u16 As1[128*64];
    __shared__ u16 Bs0[128*64];
    __shared__ u16 Bs1[128*64];

    const int bid = blockIdx.x;
    if (bid < 512) {
        // xovT[e][k] = sum_d ovT[e][d] * xb[k][d]  (M=1024, N=8192, K=1024)
        const int l = (bid & 7) * 64 + (bid >> 3);
        const int mt = l % 8;
        const int nt = l / 8;
        gemm_core<128,128,2,2, 1,0,0,0,0,0>(
            As0, As1, Bs0, Bs1,
            ovT, xb, xovT, nullptr, nullptr,
            mt, nt, D_MODEL, D_MODEL, D_MODEL, BS_ROWS, 1.0f, 0, 0);
    } else {
        // scores: Pu = exp(qm @ kk^T / D), causal-zeroed, rowsum atomics
        const int sb = bid - 512;
        const int l = (sb & 7) * 128 + (sb >> 3);
        const int f = (l >> 5) & 1;
        const int p = (l & 31) | ((l >> 6) << 5);    // 0..511
        const int z = p >> 7;
        const int q = p & 127;
        const int mt = f ? 15 - (q & 15) : (q & 15);
        const int nt = f ? 15 - (q >> 4) : (q >> 4);
        if (nt > mt) return;                         // above causal diagonal
        gemm_core<128,128,2,2, 1,0,0,1,0,0>(
            As0, As1, Bs0, Bs1,
            qm + (long)z * SEQ * C_DIM,
            kk + (long)z * SEQ * C_DIM,
            sc + (long)z * SEQ * SEQ,
            nullptr,
            rowsum + (long)z * SEQ,
            mt, nt, C_DIM, C_DIM, C_DIM, SEQ, 1.0f / D_MODEL, 0, 0);
    }
}

// ---------------------------------------------------------------------------
// Split-K out-projection: out = (Pu @ xovT^T) / rowsum, fp32 out.
// mt>=8 rows (serial chains 18..32 K-steps) split into two even-step LOCAL
// K-chunks that atomicAdd into pre-zeroed d_out; mt<8 single-chunk plain
// store. Batch offsets pre-applied to base pointers (A: z*SEQ*SEQ elems;
// B: z*SEQ column offset into xovT — round-18 scheme); kt0 stays LOCAL.
// Max chain 32 -> 16 steps. 768 blocks, LPT (splits first, mt descending).
// ---------------------------------------------------------------------------
__launch_bounds__(256)
__global__ void outproj_split(const u16* __restrict__ sc,
                              const u16* __restrict__ xovT,
                              float* __restrict__ outp,
                              const float* __restrict__ rowsum)
{
    __shared__ u16 As0[128*64];
    __shared__ u16 As1[128*64];
    __shared__ u16 Bs0[128*64];
    __shared__ u16 Bs1[128*64];

    const int nwg = gridDim.x;                        // 768
    const int l   = (blockIdx.x & 7) * (nwg >> 3) + (blockIdx.x >> 3);

    int mt, nt, z, kt0, nktL, atomicPath;
    if (l < 512) {
        // split region: mt 8..15, two chunks each
        const int sid = l;
        z = sid >> 7;                                 // 128 per batch
        const int w = sid & 127;
        mt = 15 - (w >> 4);                           // 15..8, longest first
        nt = (w >> 1) & 7;
        const int ch = w & 1;
        const int nkt = 2 * (mt + 1);                 // 18..32
        const int c0n = ((mt + 1) + 1) & ~1;          // even, >= half
        if (ch == 0) { kt0 = 0;   nktL = c0n; }
        else         { kt0 = c0n; nktL = nkt - c0n; }
        atomicPath = 1;
    } else {
        // single region: mt 0..7
        const int sid = l - 512;
        z = sid >> 6;                                 // 64 per batch
        const int w = sid & 63;
        mt = 7 - (w >> 3);                            // 7..0, longest first
        nt = w & 7;
        kt0 = 0; nktL = 2 * (mt + 1);                 // 2..16
        atomicPath = 0;
    }

    const u16* Aa = sc + (long)z * SEQ * SEQ;         // batch base (A)
    const u16* Bb = xovT + (long)z * SEQ;             // batch column base (B)
    float* Cout = outp + (long)z * SEQ * D_MODEL;
    float* rsz = (float*)(rowsum + (long)z * SEQ);    // read-only here (RSCALE)

    if (atomicPath) {
        gemm_core<128,128,2,2, 0,0,0,0,1,1>(
            As0, As1, Bs0, Bs1, Aa, Bb, Cout, nullptr, rsz,
            mt, nt, SEQ, SEQ, BS_ROWS, D_MODEL, 1.0f,
            kt0, nktL);
    } else {
        gemm_core<128,128,2,2, 0,0,0,0,1,0>(
            As0, As1, Bs0, Bs1, Aa, Bb, Cout, nullptr, rsz,
            mt, nt, SEQ, SEQ, BS_ROWS, D_MODEL, 1.0f,
            kt0, nktL);
    }
}

// ---------------------------------------------------------------------------
// Merged prep: one dispatch, bid-range roles.
//   [0,2048):        x fp32->bf16 (grid-stride) + rowsum zero-fill
//   [2048,2176):     Bmat fp32->bf16
//   [2176,3200):     ov transpose->ovT
//   [3200,3328):     A transpose->AbT
//   [3328,5376):     d_out zero (32 MB, for split-K atomics)
// ---------------------------------------------------------------------------
__launch_bounds__(256)
__global__ void prep_all(const float* __restrict__ x,  u16* __restrict__ xb,
                         float* __restrict__ rowsum,
                         const float* __restrict__ Bm, u16* __restrict__ Bmb,
                         const float* __restrict__ ov, u16* __restrict__ ovT,
                         const float* __restrict__ A,  u16* __restrict__ AbT,
                         float* __restrict__ outp)
{
    __shared__ float t[32][33];
    const int bid = blockIdx.x;
    if (bid < 2048) {
        const int gid = bid * 256 + threadIdx.x;
        if (gid < BS_ROWS) rowsum[gid] = 0.f;
        const int n4 = BS_ROWS * D_MODEL / 4;
        for (int i = gid; i < n4; i += 2048 * 256) {
            float4 f = reinterpret_cast<const float4*>(x)[i];
            u16x4 o = { f2bf(f.x), f2bf(f.y), f2bf(f.z), f2bf(f.w) };
            reinterpret_cast<u16x4*>(xb)[i] = o;
        }
    } else if (bid < 2176) {
        const int gid = (bid - 2048) * 256 + threadIdx.x;
        float4 f = reinterpret_cast<const float4*>(Bm)[gid];
        u16x4 o = { f2bf(f.x), f2bf(f.y), f2bf(f.z), f2bf(f.w) };
        reinterpret_cast<u16x4*>(Bmb)[gid] = o;
    } else if (bid < 3200) {
        const int local = bid - 2176;
        const int c0 = (local & 31) * 32, r0 = (local >> 5) * 32;
        const int tx = threadIdx.x & 31, ty = threadIdx.x >> 5;
        #pragma unroll
        for (int i = 0; i < 32; i += 8)
            t[ty + i][tx] = ov[(size_t)(r0 + ty + i) * D_MODEL + c0 + tx];
        __syncthreads();
        #pragma unroll
        for (int i = 0; i < 32; i += 8)
            ovT[(size_t)(c0 + ty + i) * D_MODEL + r0 + tx] = f2bf(t[tx][ty + i]);
    } else if (bid < 3328) {
        const int local = bid - 3200;
        const int c0 = (local & 3) * 32, r0 = (local >> 2) * 32;
        const int tx = threadIdx.x & 31, ty = threadIdx.x >> 5;
        #pragma unroll
        for (int i = 0; i < 32; i += 8)
            t[ty + i][tx] = A[(size_t)(r0 + ty + i) * C_DIM + c0 + tx];
        __syncthreads();
        #pragma unroll
        for (int i = 0; i < 32; i += 8)
            AbT[(size_t)(c0 + ty + i) * D_MODEL + r0 + tx] = f2bf(t[tx][ty + i]);
    } else {
        // zero d_out: 8M floats = 2M float4; 2048 blocks x 256 thr x 4
        const int gid = (bid - 3328) * 256 + threadIdx.x;
        float4 zf = make_float4(0.f, 0.f, 0.f, 0.f);
        float4* o4 = reinterpret_cast<float4*>(outp);
        #pragma unroll
        for (int i = 0; i < 4; ++i)
            o4[(size_t)gid * 4 + i] = zf;
    }
}

// ---------------------------------------------------------------------------
extern "C" void kernel_launch(void* const* d_in, const int* in_sizes, int n_in,
                              void* d_out, int out_size, void* d_ws, size_t ws_size,
                              hipStream_t stream)
{
    const float* x    = (const float*)d_in[0];
    const float* A    = (const float*)d_in[1];
    const float* Bm   = (const float*)d_in[2];
    const float* ov   = (const float*)d_in[3];
    const float* mask = (const float*)d_in[4];
    float* outp = (float*)d_out;

    // workspace layout: ~70.3 MiB
    char* w = (char*)d_ws;
    u16* xb   = (u16*)w; w += (size_t)BS_ROWS * D_MODEL * 2;   // x bf16 row-major
    u16* AbT  = (u16*)w; w += (size_t)C_DIM * D_MODEL * 2;     // A^T [C][D]
    u16* Bmb  = (u16*)w; w += (size_t)C_DIM * D_MODEL * 2;     // Bmat [C][D]
    u16* ovT  = (u16*)w; w += (size_t)D_MODEL * D_MODEL * 2;   // ov^T [e][d]
    u16* qm   = (u16*)w; w += (size_t)BS_ROWS * C_DIM * 2;     // masked q
    u16* kk   = (u16*)w; w += (size_t)BS_ROWS * C_DIM * 2;     // k
    u16* sc   = (u16*)w; w += (size_t)BATCH * SEQ * SEQ * 2;   // Pu = exp(scores)
    u16* xovT = (u16*)w; w += (size_t)D_MODEL * BS_ROWS * 2;   // (x@ov)^T [e][k]
    float* rowsum = (float*)w; w += (size_t)BS_ROWS * 4;       // softmax denoms

    // merged prep (converts + transposes + rowsum zero + d_out zero)
    prep_all<<<5376, 256, 0, stream>>>(x, xb, rowsum, Bm, Bmb, ov, ovT, A, AbT, outp);

    // fused q & k projection: 64x64 tiles, 4 waves; 512 blocks
    qk_proj<<<512, 256, 0, stream>>>(xb, AbT, Bmb, qm, kk, mask);

    // fused dispatch, LPT: xovT (512 bids, long) + scores (1024 bids, short)
    scores_xov_fused<<<1536, 256, 0, stream>>>(qm, kk, sc, rowsum, ovT, xb, xovT);

    // out = (Pu @ xovT^T) / rowsum — split-K straggler fix, 768 blocks
    outproj_split<<<768, 256, 0, stream>>>(sc, xovT, outp, rowsum);
}

// Round 22
// 88.771 us; speedup vs baseline: 1.2350x; 1.2350x over previous
//
#include <hip/hip_runtime.h>
#include <hip/hip_bf16.h>
#include <math.h>

#define D_MODEL 1024
#define C_DIM   128
#define BATCH   4
#define SEQ     2048
#define BS_ROWS (BATCH*SEQ)

typedef float  f32x4 __attribute__((ext_vector_type(4)));
typedef short  s16x8 __attribute__((ext_vector_type(8)));
typedef unsigned short u16;
typedef unsigned short u16x4 __attribute__((ext_vector_type(4)));

__device__ inline u16 f2bf(float f){
    unsigned u = __builtin_bit_cast(unsigned, f);
    u += 0x7FFF + ((u >> 16) & 1);          // round-to-nearest-even
    return (u16)(u >> 16);
}

// async global->LDS, 16B per lane; LDS dest = wave-uniform base + lane*16
__device__ inline void gl_lds16(const u16* g, u16* l){
    __builtin_amdgcn_global_load_lds(
        (const __attribute__((address_space(1))) void*)g,
        (__attribute__((address_space(3))) void*)l,
        16, 0, 0);
}

// counted vmem wait: wait until <= N vmem instrs outstanding (this wave)
template<int N> __device__ inline void wait_vm(){
    if constexpr (N <= 0)      asm volatile("s_waitcnt vmcnt(0)" ::: "memory");
    else if constexpr (N == 4) asm volatile("s_waitcnt vmcnt(4)" ::: "memory");
    else if constexpr (N == 8) asm volatile("s_waitcnt vmcnt(8)" ::: "memory");
    else                       asm volatile("s_waitcnt vmcnt(0)" ::: "memory");
}

// ---------------------------------------------------------------------------
// gemm_core: the verified round-12/15 GEMM body (static disjoint double
// buffers, 2x-unrolled K-loop, counted vmcnt(NL), raw barriers, hoisted
// staging pointers). All batch offsets pre-applied by the caller.
// C[M,N] = scale * A[M,K] @ BT[N,K]^T for the (mt,nt) tile.
// Flags: OUT_BF16; MASK (f *= mp[off] when mp!=null); CK (causal K-extent);
// EXPSUM (P=exp, causal-zero, rowsum atomics); RSCALE (divide by rowsum).
// ---------------------------------------------------------------------------
template<int BM, int BN, int WM, int WN, int OUT_BF16, int MASK, int CK,
         int EXPSUM, int RSCALE>
__device__ __forceinline__ void gemm_core(
    u16 (&As0)[BM*64], u16 (&As1)[BM*64],
    u16 (&Bs0)[BN*64], u16 (&Bs1)[BN*64],
    const u16* __restrict__ Aa, const u16* __restrict__ Bb,
    void* __restrict__ Cout, const float* __restrict__ mp,
    float* __restrict__ rowsum,
    int mt, int nt, int K, int lda, int ldb, int ldc, float scale)
{
    constexpr int W  = WM * WN;
    constexpr int PM = BM / WM, PN = BN / WN;
    constexpr int FM = PM / 16, FN = PN / 16;
    constexpr int CA = BM / 8 / W;          // A chunks (1KB) per wave per stage
    constexpr int CB = BN / 8 / W;
    constexpr int NL = CA + CB;             // gl_lds instrs per wave per stage
    constexpr int ASZ = BM * 64, BSZ = BN * 64;

    const int tid = threadIdx.x, lane = tid & 63, wave = tid >> 6;
    const int wr = wave / WN, wc = wave % WN;
    const int mbase = mt * BM, nbase = nt * BN;
    int Keff = K;
    if (CK) { int ke = (mt + 1) * BM; Keff = ke < K ? ke : K; }
    const int nkt = Keff >> 6;              // even by construction

    f32x4 acc[FM][FN];
    #pragma unroll
    for (int m = 0; m < FM; ++m)
        #pragma unroll
        for (int n = 0; n < FN; ++n) acc[m][n] = (f32x4){0.f,0.f,0.f,0.f};

    const int sr  = lane >> 3;                 // row within 8-row chunk
    const int sc8 = (lane & 7) ^ sr;           // XOR-swizzled 16B col slot

    // hoisted staging pointers: one per chunk, advanced 64 elts per STAGE
    const u16* aptr[CA];
    const u16* bptr[CB];
    #pragma unroll
    for (int s = 0; s < CA; ++s)
        aptr[s] = Aa + (size_t)(mbase + (wave * CA + s) * 8 + sr) * lda + sc8 * 8;
    #pragma unroll
    for (int s = 0; s < CB; ++s)
        bptr[s] = Bb + (size_t)(nbase + (wave * CB + s) * 8 + sr) * ldb + sc8 * 8;

    auto STAGE = [&](u16 (&Ad)[ASZ], u16 (&Bd)[BSZ]) {
        #pragma unroll
        for (int s = 0; s < CA; ++s) { gl_lds16(aptr[s], &Ad[(wave * CA + s) * 512]); aptr[s] += 64; }
        #pragma unroll
        for (int s = 0; s < CB; ++s) { gl_lds16(bptr[s], &Bd[(wave * CB + s) * 512]); bptr[s] += 64; }
    };

    auto COMPUTE = [&](const u16 (&Ap)[ASZ], const u16 (&Bp)[BSZ]) {
        #pragma unroll
        for (int ks = 0; ks < 2; ++ks) {
            s16x8 af[FM], bfr[FN];
            const int k8 = ks * 4 + (lane >> 4);
            #pragma unroll
            for (int m = 0; m < FM; ++m) {
                const int row = wr * PM + m * 16 + (lane & 15);
                af[m] = *(const s16x8*)&Ap[row * 64 + ((k8 ^ (row & 7)) << 3)];
            }
            #pragma unroll
            for (int n = 0; n < FN; ++n) {
                const int row = wc * PN + n * 16 + (lane & 15);
                bfr[n] = *(const s16x8*)&Bp[row * 64 + ((k8 ^ (row & 7)) << 3)];
            }
            #pragma unroll
            for (int m = 0; m < FM; ++m)
                #pragma unroll
                for (int n = 0; n < FN; ++n)
                    acc[m][n] = __builtin_amdgcn_mfma_f32_16x16x32_bf16(af[m], bfr[n], acc[m][n], 0, 0, 0);
        }
    };

    // prologue: tile 0 into buf0
    STAGE(As0, Bs0);
    for (int t = 0; t < nkt; t += 2) {
        // ---- phase A: compute tile t from buf0; prefetch t+1 into buf1 ----
        STAGE(As1, Bs1);                 // t+1 < nkt always (nkt even)
        wait_vm<NL>();                   // retire tile t's loads only
        __builtin_amdgcn_s_barrier();    // buf0 complete for all waves
        COMPUTE(As0, Bs0);
        __builtin_amdgcn_s_barrier();    // all waves done reading buf0
        // ---- phase B: compute tile t+1 from buf1; prefetch t+2 into buf0 ----
        if (t + 2 < nkt) { STAGE(As0, Bs0); wait_vm<NL>(); }
        else             { wait_vm<0>(); }
        __builtin_amdgcn_s_barrier();    // buf1 complete
        COMPUTE(As1, Bs1);
        __builtin_amdgcn_s_barrier();    // all waves done reading buf1
    }

    // epilogue: C/D layout col=lane&15, row=(lane>>4)*4+r (m89-verified)
    const int lr = (lane >> 4) * 4, lc = lane & 15;
    float rs[FM][4];
    if (EXPSUM) {
        #pragma unroll
        for (int m = 0; m < FM; ++m)
            #pragma unroll
            for (int r = 0; r < 4; ++r) rs[m][r] = 0.f;
    }
    #pragma unroll
    for (int m = 0; m < FM; ++m) {
        #pragma unroll
        for (int n = 0; n < FN; ++n) {
            const int gr = mbase + wr * PM + m * 16 + lr;
            const int gc = nbase + wc * PN + n * 16 + lc;
            #pragma unroll
            for (int r = 0; r < 4; ++r) {
                float f = acc[m][n][r] * scale;
                if (EXPSUM) {
                    f = (gc <= gr + r) ? __expf(f) : 0.f;   // causal + exp
                    rs[m][r] += f;
                }
                if (RSCALE) f /= rowsum[gr + r];
                const size_t off = (size_t)(gr + r) * ldc + gc;
                if (MASK) { if (mp) f *= mp[off]; }
                if (OUT_BF16) ((u16*)Cout)[off] = f2bf(f);
                else          ((float*)Cout)[off] = f;
            }
        }
    }
    if (EXPSUM) {
        #pragma unroll
        for (int m = 0; m < FM; ++m) {
            #pragma unroll
            for (int r = 0; r < 4; ++r) {
                float v = rs[m][r];
                v += __shfl_xor(v, 1); v += __shfl_xor(v, 2);
                v += __shfl_xor(v, 4); v += __shfl_xor(v, 8);
                if ((lane & 15) == 0) {
                    const int gr = mbase + wr * PM + m * 16 + lr + r;
                    atomicAdd(rowsum + gr, v);
                }
            }
        }
    }
}

// ---------------------------------------------------------------------------
// gemm_bt wrapper: decode (XCD swizzle / ORD / PAIR / QKF / CSKIP), then core.
// PAIR=1 (out-proj, nwg=512, gx=16, gy=8): co-resident (l, l^32) get
//   complementary mt -> per-CU causal work sums to const; same (nt,z).
// ---------------------------------------------------------------------------
template<int BM, int BN, int WM, int WN, int OUT_BF16, int MASK, int CSKIP,
         int CK, int QKF, int EXPSUM, int RSCALE, int ORD, int PAIR>
__launch_bounds__(WM*WN*64)
__global__ void gemm_bt(const u16* __restrict__ Ag, const u16* __restrict__ Bg,
                        const u16* __restrict__ Bg2,
                        void* __restrict__ Cg, void* __restrict__ Cg2,
                        const float* __restrict__ maskp,
                        float* __restrict__ rowsum,
                        int gx, int gy,
                        int K, int lda, int ldb, int ldc,
                        long sA, long sB, long sC, float scale)
{
    constexpr int ASZ = BM * 64, BSZ = BN * 64;
    __shared__ u16 As0[ASZ];
    __shared__ u16 As1[ASZ];
    __shared__ u16 Bs0[BSZ];
    __shared__ u16 Bs1[BSZ];

    // XCD-chunked bijective swizzle (T1): nwg % 8 == 0 for all launches
    const int nwg = gridDim.x;
    const int l   = (blockIdx.x & 7) * (nwg >> 3) + (blockIdx.x >> 3);
    int mt, nt, z, path = 0;
    if (PAIR == 1) {
        const int pairid = l & 7;
        const int f      = (l >> 5) & 1;
        mt = f ? (gx - 1 - pairid) : pairid;
        const int ntz = ((l >> 3) & 3) | (((l >> 6) & 7) << 2);
        nt = ntz & 7;
        z  = ntz >> 3;
    } else if (ORD == 0) {
        mt = l % gx; const int r = l / gx; nt = r % gy; z = r / gy;
    } else {
        nt = l % gy; const int r = l / gy; mt = r % gx; z = r / gx;
    }
    if (QKF) { constexpr int NT = C_DIM / BN; path = nt / NT; nt = nt % NT; }
    if (CSKIP && nt * BN >= (mt + 1) * BM) return;   // above causal diagonal

    const bool kpath = QKF && path;
    const u16* Aa = Ag + (long)z * sA;
    const u16* Bb = (kpath ? Bg2 : Bg) + (long)z * sB;
    void* CoutBase = kpath ? Cg2 : Cg;
    void* Cout = OUT_BF16 ? (void*)((u16*)CoutBase + (long)z * sC)
                          : (void*)((float*)CoutBase + (long)z * sC);
    const float* mp = (MASK && !kpath && maskp) ? maskp + (long)z * sC : nullptr;
    float* rsz = rowsum ? rowsum + (long)z * SEQ : nullptr;

    gemm_core<BM,BN,WM,WN,OUT_BF16,MASK,CK,EXPSUM,RSCALE>(
        As0, As1, Bs0, Bs1, Aa, Bb, Cout, mp, rsz,
        mt, nt, K, lda, ldb, ldc, scale);
}

// ---------------------------------------------------------------------------
// Fused scores + xovT dispatch, LPT-ordered: the LONG xovT blocks (16
// K-tiles) occupy bids [0,512) so they start at t=0; the short scores
// blocks (<=2 K-tiles) fill bids [512,1536) and drain into vacated slots.
// ---------------------------------------------------------------------------
__launch_bounds__(256)
__global__ void scores_xov_fused(const u16* __restrict__ qm,
                                 const u16* __restrict__ kk,
                                 u16* __restrict__ sc,
                                 float* __restrict__ rowsum,
                                 const u16* __restrict__ ovT,
                                 const u16* __restrict__ xb,
                                 u16* __restrict__ xovT)
{
    __shared__ u16 As0[128*64];
    __shared__ u16 As1[128*64];
    __shared__ u16 Bs0[128*64];
    __shared__ u16 Bs1[128*64];

    const int bid = blockIdx.x;
    if (bid < 512) {
        // xovT[e][k] = sum_d ovT[e][d] * xb[k][d]  (M=1024, N=8192, K=1024)
        // ORD=0 decode over local grid (nwg=512, gx=8, gy=64, z=0)
        const int l = (bid & 7) * 64 + (bid >> 3);
        const int mt = l % 8;
        const int nt = l / 8;                        // 0..63
        gemm_core<128,128,2,2, 1,0,0,0,0>(
            As0, As1, Bs0, Bs1,
            ovT, xb, xovT, nullptr, nullptr,
            mt, nt, D_MODEL, D_MODEL, D_MODEL, BS_ROWS, 1.0f);
    } else {
        // scores: Pu = exp(qm @ kk^T / D), causal-zeroed, rowsum atomics
        // PAIR=2 decode (local nwg=1024, gx=gy=16, BATCH=4) — verified
        const int sb = bid - 512;                    // 0..1023 (512%8==0)
        const int l = (sb & 7) * 128 + (sb >> 3);
        const int f = (l >> 5) & 1;
        const int p = (l & 31) | ((l >> 6) << 5);    // 0..511
        const int z = p >> 7;
        const int q = p & 127;
        const int mt = f ? 15 - (q & 15) : (q & 15);
        const int nt = f ? 15 - (q >> 4) : (q >> 4);
        if (nt > mt) return;                         // above causal diagonal
        gemm_core<128,128,2,2, 1,0,0,1,0>(
            As0, As1, Bs0, Bs1,
            qm + (long)z * SEQ * C_DIM,
            kk + (long)z * SEQ * C_DIM,
            sc + (long)z * SEQ * SEQ,
            nullptr,
            rowsum + (long)z * SEQ,
            mt, nt, C_DIM, C_DIM, C_DIM, SEQ, 1.0f / D_MODEL);
    }
}

// ---------------------------------------------------------------------------
// Merged prep: one dispatch, bid-range roles.
//   [0,2048):        x fp32->bf16 (grid-stride) + rowsum zero-fill
//   [2048,2176):     Bmat fp32->bf16 (exact cover)
//   [2176,3200):     ov transpose->ovT  (32x32 tiles, 32x32 grid)
//   [3200,3328):     A transpose->AbT   (4x32 grid)
// ---------------------------------------------------------------------------
__launch_bounds__(256)
__global__ void prep_all(const float* __restrict__ x,  u16* __restrict__ xb,
                         float* __restrict__ rowsum,
                         const float* __restrict__ Bm, u16* __restrict__ Bmb,
                         const float* __restrict__ ov, u16* __restrict__ ovT,
                         const float* __restrict__ A,  u16* __restrict__ AbT)
{
    __shared__ float t[32][33];
    const int bid = blockIdx.x;
    if (bid < 2048) {
        const int gid = bid * 256 + threadIdx.x;
        if (gid < BS_ROWS) rowsum[gid] = 0.f;
        const int n4 = BS_ROWS * D_MODEL / 4;
        for (int i = gid; i < n4; i += 2048 * 256) {
            float4 f = reinterpret_cast<const float4*>(x)[i];
            u16x4 o = { f2bf(f.x), f2bf(f.y), f2bf(f.z), f2bf(f.w) };
            reinterpret_cast<u16x4*>(xb)[i] = o;
        }
    } else if (bid < 2176) {
        const int gid = (bid - 2048) * 256 + threadIdx.x;   // exact cover
        float4 f = reinterpret_cast<const float4*>(Bm)[gid];
        u16x4 o = { f2bf(f.x), f2bf(f.y), f2bf(f.z), f2bf(f.w) };
        reinterpret_cast<u16x4*>(Bmb)[gid] = o;
    } else if (bid < 3200) {
        // ov[D][D] -> ovT[c][r]
        const int local = bid - 2176;
        const int c0 = (local & 31) * 32, r0 = (local >> 5) * 32;
        const int tx = threadIdx.x & 31, ty = threadIdx.x >> 5;
        #pragma unroll
        for (int i = 0; i < 32; i += 8)
            t[ty + i][tx] = ov[(size_t)(r0 + ty + i) * D_MODEL + c0 + tx];
        __syncthreads();
        #pragma unroll
        for (int i = 0; i < 32; i += 8)
            ovT[(size_t)(c0 + ty + i) * D_MODEL + r0 + tx] = f2bf(t[tx][ty + i]);
    } else {
        // A[D][C] -> AbT[c][r]
        const int local = bid - 3200;
        const int c0 = (local & 3) * 32, r0 = (local >> 2) * 32;
        const int tx = threadIdx.x & 31, ty = threadIdx.x >> 5;
        #pragma unroll
        for (int i = 0; i < 32; i += 8)
            t[ty + i][tx] = A[(size_t)(r0 + ty + i) * C_DIM + c0 + tx];
        __syncthreads();
        #pragma unroll
        for (int i = 0; i < 32; i += 8)
            AbT[(size_t)(c0 + ty + i) * D_MODEL + r0 + tx] = f2bf(t[tx][ty + i]);
    }
}

// ---------------------------------------------------------------------------
extern "C" void kernel_launch(void* const* d_in, const int* in_sizes, int n_in,
                              void* d_out, int out_size, void* d_ws, size_t ws_size,
                              hipStream_t stream)
{
    const float* x    = (const float*)d_in[0];
    const float* A    = (const float*)d_in[1];
    const float* Bm   = (const float*)d_in[2];
    const float* ov   = (const float*)d_in[3];
    const float* mask = (const float*)d_in[4];

    // workspace layout: ~70.3 MiB
    char* w = (char*)d_ws;
    u16* xb   = (u16*)w; w += (size_t)BS_ROWS * D_MODEL * 2;   // x bf16 row-major
    u16* AbT  = (u16*)w; w += (size_t)C_DIM * D_MODEL * 2;     // A^T [C][D]
    u16* Bmb  = (u16*)w; w += (size_t)C_DIM * D_MODEL * 2;     // Bmat [C][D]
    u16* ovT  = (u16*)w; w += (size_t)D_MODEL * D_MODEL * 2;   // ov^T [e][d]
    u16* qm   = (u16*)w; w += (size_t)BS_ROWS * C_DIM * 2;     // masked q
    u16* kk   = (u16*)w; w += (size_t)BS_ROWS * C_DIM * 2;     // k
    u16* sc   = (u16*)w; w += (size_t)BATCH * SEQ * SEQ * 2;   // Pu = exp(scores)
    u16* xovT = (u16*)w; w += (size_t)D_MODEL * BS_ROWS * 2;   // (x@ov)^T [e][k]
    float* rowsum = (float*)w; w += (size_t)BS_ROWS * 4;       // softmax denoms

    // merged prep (converts + transposes + rowsum zero): one dispatch
    prep_all<<<3328, 256, 0, stream>>>(x, xb, rowsum, Bm, Bmb, ov, ovT, A, AbT);

    // fused q & k projection: 64x64 tiles, 4 waves; 512 blocks; ORD=1
    gemm_bt<64,64,2,2, 1,1,0,0,1,0,0, 1,0><<<512, 256, 0, stream>>>(
        xb, AbT, Bmb, qm, kk, mask, nullptr,
        /*gx*/128, /*gy*/4,
        D_MODEL, D_MODEL, D_MODEL, C_DIM, 0, 0, 0, 1.0f);

    // fused dispatch, LPT: xovT (512 bids, long) + scores (1024 bids, short)
    scores_xov_fused<<<1536, 256, 0, stream>>>(qm, kk, sc, rowsum, ovT, xb, xovT);

    // out = (Pu @ xovT^T) / rowsum   (per batch, causal K-extent, fp32 out)
    // 128x128, 4 waves; 512 blocks; PAIR=1: complementary-mt pairs
    gemm_bt<128,128,2,2, 0,0,0,1,0,0,1, 0,1><<<512, 256, 0, stream>>>(
        sc, xovT, nullptr, d_out, nullptr, nullptr, rowsum,
        /*gx*/16, /*gy*/8,
        SEQ, SEQ, BS_ROWS, D_MODEL,
        (long)SEQ * SEQ, (long)SEQ /*batch col offset in xovT*/, (long)SEQ * D_MODEL, 1.0f);
}